// Round 18
// baseline (93.897 us; speedup 1.0000x reference)
//
#include <hip/hip_runtime.h>
#include <hip/hip_bf16.h>

#define S_LEN 2048
#define BATCH 4
#define NH 8
#define DK 16
#define DM 256
#define DP 128           // NH*DK
#define L2E 1.4426950408889634f

typedef short bf16x8 __attribute__((ext_vector_type(8)));
typedef short short4v __attribute__((ext_vector_type(4)));
typedef float f32x16 __attribute__((ext_vector_type(16)));

__device__ __forceinline__ short f2bf(float x) {
    __hip_bfloat16 h = __float2bfloat16(x);
    return __builtin_bit_cast(short, h);
}

union Frag { bf16x8 v; short4v h2[2]; };

// ---------------- Kernel A: main1 = proj_mfma U vinit U pack_mask ----------
// [0,768): proj (in-register W gather); [768,1280): vinit; [1280,5376): pack
__global__ __launch_bounds__(256) void main1(
    const void* __restrict__ mraw, unsigned long long* __restrict__ ms64,
    const float* __restrict__ Xq, const float* __restrict__ Xk, const float* __restrict__ Xv,
    const float* __restrict__ Wq, const float* __restrict__ Wk, const float* __restrict__ Wv,
    short* __restrict__ Qt, short* __restrict__ Kb, short* __restrict__ Vb)
{
    __shared__ short xs_s[32 * 260];            // proj only; pitch 260 (2-way free)
    __shared__ int isBool;                      // pack only
    const int bi = blockIdx.x;
    const int t = threadIdx.x;

    if (bi < 768) {
        // ---------------- proj_mfma ----------------
        const int inp = bi >> 8;                // 0=Q,1=K,2=V
        const int s0 = (bi & 255) * 32;
        {
            // coalesced: each wave-load instruction covers one full 1KB X row
            const float* xbase = ((inp == 0) ? Xq : (inp == 1) ? Xk : Xv) + (size_t)s0 * 256;
            #pragma unroll
            for (int u = 0; u < 8; ++u) {
                const int idx = u * 1024 + t * 4;   // linear float index in 32x256 tile
                const int row = idx >> 8, col = idx & 255;
                float4 xv = *(const float4*)(xbase + idx);
                short4v o = { f2bf(xv.x), f2bf(xv.y), f2bf(xv.z), f2bf(xv.w) };
                *(short4v*)&xs_s[row * 260 + col] = o;
            }
        }

        const int wave = t >> 6, lane = t & 63;
        const int lq = lane & 31, hi = lane >> 5;
        const int c = wave * 32 + lq;           // out col 0..127

        // per-lane W fragments from f32 (lane-consecutive in c; L2-hot)
        const float* W = (inp == 0) ? Wq : (inp == 1) ? Wk : Wv;
        const float scale = (inp == 0) ? 0.25f * L2E : 1.0f;   // fold 1/sqrt(dk)*log2e into Wq
        Frag wf[16];
        #pragma unroll
        for (int kb = 0; kb < 16; ++kb) {
            const int k0 = kb * 16 + 4 * hi;
            union { bf16x8 v; short s[8]; } o;
            #pragma unroll
            for (int e = 0; e < 4; ++e) {
                o.s[e]     = f2bf(W[(size_t)(k0 + e) * DP + c] * scale);
                o.s[4 + e] = f2bf(W[(size_t)(k0 + 8 + e) * DP + c] * scale);
            }
            wf[kb].v = o.v;
        }
        __syncthreads();

        f32x16 acc;
        #pragma unroll
        for (int i = 0; i < 16; ++i) acc[i] = 0.f;

        #pragma unroll
        for (int kb = 0; kb < 16; ++kb) {
            Frag af;
            af.h2[0] = *(const short4v*)&xs_s[lq * 260 + kb*16 + 4*hi];
            af.h2[1] = *(const short4v*)&xs_s[lq * 260 + kb*16 + 8 + 4*hi];
            acc = __builtin_amdgcn_mfma_f32_32x32x16_bf16(af.v, wf[kb].v, acc, 0, 0, 0);
        }

        // D: col(lane&31)=c, row(reg r)=s0 + (r&3)+8*(r>>2)+4*hi
        const int b = s0 >> 11, sl = s0 & (S_LEN - 1);
        const int h = c >> 4, d = c & 15;
        if (inp == 1) {
            #pragma unroll
            for (int r = 0; r < 16; ++r) {
                const int s = sl + (r & 3) + 8*(r >> 2) + 4*hi;
                Kb[(((size_t)(b * NH + h)) * S_LEN + s) * DK + d] = f2bf(acc[r]);
            }
        } else {
            short* base = (inp == 0)
                ? Qt + (((size_t)(b * NH + h)) * 16 + d) * S_LEN + sl
                : Vb + (((size_t)(b * NH + h)) * 32 + d) * S_LEN + sl;
            #pragma unroll
            for (int g = 0; g < 4; ++g) {
                short4v vv = { f2bf(acc[4*g]), f2bf(acc[4*g+1]), f2bf(acc[4*g+2]), f2bf(acc[4*g+3]) };
                *(short4v*)(base + 8*g + 4*hi) = vv;
            }
        }
    } else if (bi < 1280) {
        // ---------------- vinit: V ones-rows 16,20 = 1.0 ----------------
        const int tid = (bi - 768) * 256 + t;   // 131072 total
        const int bh = tid >> 12;
        const int rem = tid & 4095;
        const int row = 16 + (rem >> 11) * 4;   // 16 or 20
        const int s = rem & 2047;
        Vb[((size_t)bh * 32 + row) * S_LEN + s] = (short)0x3F80;  // bf16 1.0
    } else {
        // ---------------- pack_mask: per-block dtype detect, ROW-major -----
        const size_t kbase0 = (size_t)(bi - 1280) * 4096;
        if (t == 0) isBool = 0;
        __syncthreads();
        {
            unsigned int u = ((const unsigned int*)mraw)[(kbase0 >> 2) + t * 4];
            if (u & 0xFFFFFF00u) isBool = 1;    // benign same-value race
        }
        __syncthreads();

        const int lane = t & 63;
        const size_t kbase = kbase0 + (size_t)(t >> 6) * 1024;   // 16 groups/wave
        int v[16];
        if (!isBool) {
            const int* p = (const int*)mraw + kbase + lane;
            #pragma unroll
            for (int g = 0; g < 16; ++g) v[g] = p[g * 64];
        } else {
            const unsigned char* p = (const unsigned char*)mraw + kbase + lane;
            #pragma unroll
            for (int g = 0; g < 16; ++g) v[g] = p[g * 64];
        }

        const size_t row = kbase >> 11;
        const int w0 = (int)(kbase & 2047) >> 6;

        unsigned long long myw = 0;
        #pragma unroll
        for (int g = 0; g < 16; ++g) {
            const unsigned long long W = __ballot(v[g] != 0);
            myw = (lane == g) ? W : myw;
        }
        if (lane < 16) ms64[row * 32 + w0 + lane] = myw;   // one 128B store/wave
    }
}

// ---------------- Kernel B: attention, in-block split-K --------------------
// grid (S/128, B*H); block 512 = 8 waves. Waves 0-3: tiles 0-7; waves 4-7:
// tiles 8-15 (same 128 q-rows). In-block combine -> normalized f32 ctx.
__global__ __launch_bounds__(512, 4) void attn_mfma(
    const short* __restrict__ Qt, const short* __restrict__ Kb, const short* __restrict__ Vb,
    const unsigned long long* __restrict__ ms64, float* __restrict__ ctx)
{
    __shared__ short kt_s[2][128 * 20];   // per-half K tile: pitch 20 shorts
    __shared__ short vt_s[2][32 * 132];   // per-half V^T tile: pitch 132 shorts
    __shared__ float cmb[256][9];         // half-B partials (8 ctx + l)

    const int bh = blockIdx.y;
    const int b = bh >> 3, h = bh & 7;
    const int t = threadIdx.x;
    const int half = t >> 8;              // 0: tiles 0-7, 1: tiles 8-15
    const int th = t & 255;               // within-half thread id
    const int wv = (t >> 6) & 3;          // wave within half
    const int lane = t & 63;
    const int lq = lane & 31, hi = lane >> 5;
    const int qrow = blockIdx.x * 128 + wv * 32 + lq;

    Frag qf;
    {
        // Q^T [bh][16][S]: 8 scalar reads, coalesced across lanes
        const short* qt = Qt + (size_t)bh * 16 * S_LEN + qrow;
        #pragma unroll
        for (int j = 0; j < 4; ++j) {
            qf.h2[0][j] = qt[(size_t)(4*hi + j) * S_LEN];
            qf.h2[1][j] = qt[(size_t)(8 + 4*hi + j) * S_LEN];
        }
    }

    f32x16 acc;
    #pragma unroll
    for (int i = 0; i < 16; ++i) acc[i] = 0.f;

    const short* kbase = Kb + (size_t)bh * S_LEN * DK;
    const short* vbase = Vb + (size_t)bh * 32 * S_LEN;
    const unsigned long long* mrow = ms64 + ((size_t)b * S_LEN + qrow) * 32;

    for (int i = 0; i < 8; ++i) {
        const int tile = half * 8 + i;
        const int k0 = tile * 128;

        // ---- stage this half's K tile (4KB) and V^T tile (8.25KB)
        {
            const uint4 kv = *(const uint4*)(kbase + (size_t)k0 * DK + th * 8);
            short* kdst = &kt_s[half][(th >> 1) * 20 + (th & 1) * 8];
            *(uint2*)(kdst)     = *(uint2*)&kv;
            *(uint2*)(kdst + 4) = *((uint2*)&kv + 1);

            const short* vsrc = vbase + (size_t)(th >> 3) * S_LEN + k0 + (th & 7) * 16;
            uint4 v0 = *(const uint4*)(vsrc);
            uint4 v1 = *(const uint4*)(vsrc + 8);
            short* vdst = &vt_s[half][(th >> 3) * 132 + (th & 7) * 16];
            *(uint2*)(vdst)      = *(uint2*)&v0;
            *(uint2*)(vdst + 4)  = *((uint2*)&v0 + 1);
            *(uint2*)(vdst + 8)  = *(uint2*)&v1;
            *(uint2*)(vdst + 12) = *((uint2*)&v1 + 1);
        }
        __syncthreads();

        const ulonglong2 mw = *(const ulonglong2*)(mrow + tile * 2);
        const unsigned long long W64a = mw.x, W64b = mw.y;

        #pragma unroll
        for (int kt = 0; kt < 4; ++kt) {
            // mask bits: key(r) = 32*(kt&1) + 4*hi + (r&3)+8*(r>>2) within word kt>>1
            const unsigned int W = (unsigned int)(((kt < 2) ? W64a : W64b)
                                                  >> (32*(kt & 1) + 4*hi));
            f32x16 ci;
            #pragma unroll
            for (int r = 0; r < 16; ++r) {
                const int bit = (r & 3) + 8*(r >> 2);
                ci[r] = __int_as_float(((int)(W << (31 - bit)) >> 31) & 0xC2C80000);
            }

            // QK^T for 32 keys (log2-domain scores via scaled Wq)
            Frag kf;
            kf.h2[0] = *(const short4v*)&kt_s[half][(kt*32 + lq) * 20 + 4*hi];
            kf.h2[1] = *(const short4v*)&kt_s[half][(kt*32 + lq) * 20 + 8 + 4*hi];
            f32x16 p = __builtin_amdgcn_mfma_f32_32x32x16_bf16(kf.v, qf.v, ci, 0, 0, 0);

            #pragma unroll
            for (int r = 0; r < 16; ++r) p[r] = __builtin_amdgcn_exp2f(p[r]);

            // PV: 2 MFMAs of 16 keys; packed bf16 convert
            #pragma unroll
            for (int j = 0; j < 2; ++j) {
                union { bf16x8 v; unsigned int u[4]; } pf;
                #pragma unroll
                for (int e = 0; e < 4; ++e) {
                    asm("v_cvt_pk_bf16_f32 %0, %1, %2"
                        : "=v"(pf.u[e]) : "v"(p[j*8 + 2*e]), "v"(p[j*8 + 2*e + 1]));
                }
                Frag vf;
                const int vo = lq * 132 + (kt*2 + j) * 16 + 4*hi;
                vf.h2[0] = *(const short4v*)&vt_s[half][vo];
                vf.h2[1] = *(const short4v*)&vt_s[half][vo + 8];
                acc = __builtin_amdgcn_mfma_f32_32x32x16_bf16(vf.v, pf.v, acc, 0, 0, 0);
            }
        }
        __syncthreads();   // protect LDS before next tile's stage
    }

    // ---- in-block combine: half B posts partials, half A normalizes+stores
    if (half == 1) {
        #pragma unroll
        for (int e = 0; e < 8; ++e) cmb[th][e] = acc[e];
        cmb[th][8] = acc[8];
    }
    __syncthreads();
    if (half == 0) {
        const float invl = 1.0f / (acc[8] + cmb[th][8]);
        float* cbase = ctx + ((size_t)b * S_LEN + qrow) * DP + h * DK;
        float4 o1 = { (acc[0] + cmb[th][0]) * invl, (acc[1] + cmb[th][1]) * invl,
                      (acc[2] + cmb[th][2]) * invl, (acc[3] + cmb[th][3]) * invl };
        float4 o2 = { (acc[4] + cmb[th][4]) * invl, (acc[5] + cmb[th][5]) * invl,
                      (acc[6] + cmb[th][6]) * invl, (acc[7] + cmb[th][7]) * invl };
        *(float4*)(cbase + 4*hi) = o1;
        *(float4*)(cbase + 8 + 4*hi) = o2;
    }
}

// ---------------- Kernel C: FC (ctx @ Wfc) + LayerNorm ---------------------
// 8 rows per block; ctx staged with coalesced float4 loads (no combine).
__global__ __launch_bounds__(256) void fc_ln(
    const float* __restrict__ ctx, const float* __restrict__ Wfc,
    const float* __restrict__ gamma, const float* __restrict__ beta,
    float* __restrict__ out)
{
    __shared__ float cs[8][DP];
    __shared__ float ys[8][256];
    __shared__ float red[16];
    const int t = threadIdx.x;
    const int row0 = blockIdx.x * 8;

    {
        const int idx = t * 4;
        const int r = idx >> 7, k = idx & 127;
        *(float4*)&cs[r][k] = *(const float4*)(ctx + (size_t)(row0 + r) * DP + k);
    }
    __syncthreads();

    float acc[8] = {0,0,0,0,0,0,0,0};
    for (int k = 0; k < DP; k += 4) {
        const float w0 = Wfc[(k+0)*DM + t];
        const float w1 = Wfc[(k+1)*DM + t];
        const float w2 = Wfc[(k+2)*DM + t];
        const float w3 = Wfc[(k+3)*DM + t];
        #pragma unroll
        for (int r = 0; r < 8; ++r) {
            float4 x = *(const float4*)&cs[r][k];
            acc[r] = fmaf(x.x, w0, fmaf(x.y, w1, fmaf(x.z, w2, fmaf(x.w, w3, acc[r]))));
        }
    }

    #pragma unroll
    for (int r = 0; r < 8; ++r) ys[r][t] = acc[r];
    __syncthreads();

    const int w = t >> 6, lj = t & 63;
    #pragma unroll
    for (int rr = 0; rr < 2; ++rr) {
        const int r = w * 2 + rr;
        float a0 = ys[r][lj], a1 = ys[r][lj+64], a2 = ys[r][lj+128], a3 = ys[r][lj+192];
        float s1 = a0 + a1 + a2 + a3;
        float s2 = a0*a0 + a1*a1 + a2*a2 + a3*a3;
        #pragma unroll
        for (int off = 32; off; off >>= 1) {
            s1 += __shfl_xor(s1, off);
            s2 += __shfl_xor(s2, off);
        }
        if (lj == 0) {
            float mu = s1 * (1.0f/256.0f);
            float var = s2 * (1.0f/256.0f) - mu*mu;
            red[r*2]     = mu;
            red[r*2 + 1] = rsqrtf(var + 1e-5f);
        }
    }
    __syncthreads();

    const float g = gamma[t], be = beta[t];
    #pragma unroll
    for (int r = 0; r < 8; ++r) {
        float y = (acc[r] - red[r*2]) * red[r*2 + 1];
        out[(size_t)(row0 + r) * DM + t] = fmaf(y, g, be);
    }
}

extern "C" void kernel_launch(void* const* d_in, const int* in_sizes, int n_in,
                              void* d_out, int out_size, void* d_ws, size_t ws_size,
                              hipStream_t stream)
{
    const float* Xq = (const float*)d_in[0];
    const float* Xk = (const float*)d_in[1];
    const float* Xv = (const float*)d_in[2];
    const void* mask_raw = d_in[3];
    const float* Wq  = (const float*)d_in[4];
    const float* Wk  = (const float*)d_in[5];
    const float* Wv  = (const float*)d_in[6];
    const float* Wfc = (const float*)d_in[7];
    const float* gamma = (const float*)d_in[8];
    const float* beta  = (const float*)d_in[9];
    float* out = (float*)d_out;

    const size_t headsz = (size_t)BATCH * NH * S_LEN * DK;      // 1,048,576 elems
    const size_t maskelems = (size_t)BATCH * S_LEN * S_LEN;     // 16.8M

    char* wsb = (char*)d_ws;
    short* Qt = (short*)wsb;                              // 2 MB ([bh][16][S])
    short* Kb = Qt + headsz;                              // 2 MB ([bh][S][16])
    short* Vb = Kb + headsz;                              // 4 MB ([bh][32][S])
    unsigned long long* msk = (unsigned long long*)(Vb + 2 * headsz);  // 2 MB row-major
    float* ctx = (float*)(msk + maskelems / 64);          // 4 MB f32 [B,S,128]

    main1<<<dim3(768 + 512 + (unsigned)(maskelems / 4096)), dim3(256), 0, stream>>>(
        mask_raw, msk, Xq, Xk, Xv, Wq, Wk, Wv, Qt, Kb, Vb);
    attn_mfma<<<dim3(S_LEN / 128, BATCH * NH), dim3(512), 0, stream>>>(
        Qt, Kb, Vb, msk, ctx);
    fc_ln<<<dim3(BATCH * S_LEN / 8), dim3(256), 0, stream>>>(ctx, Wfc, gamma, beta, out);
}

// Round 20
// 71.315 us; speedup vs baseline: 1.3166x; 1.3166x over previous
//
#include <hip/hip_runtime.h>
#include <hip/hip_bf16.h>

#define S_LEN 2048
#define BATCH 4
#define NH 8
#define DK 16
#define DM 256
#define DP 128           // NH*DK
#define L2E 1.4426950408889634f

typedef short bf16x8 __attribute__((ext_vector_type(8)));
typedef short short4v __attribute__((ext_vector_type(4)));
typedef float f32x16 __attribute__((ext_vector_type(16)));

__device__ __forceinline__ short f2bf(float x) {
    __hip_bfloat16 h = __float2bfloat16(x);
    return __builtin_bit_cast(short, h);
}

union Frag { bf16x8 v; short4v h2[2]; };

// ---------------- Kernel A: main1 = proj_mfma U vinit U pack_mask ----------
// [0,768): proj (in-register W gather); [768,1280): vinit; [1280,5376): pack.
// pack emits the PLAIN row-major bitmask (bit j of word w = mask[row][64w+j]),
// built from vectorized uint4 loads + in-register bit compression + shfl.
__global__ __launch_bounds__(256) void main1(
    const void* __restrict__ mraw, unsigned long long* __restrict__ ms64,
    const float* __restrict__ Xq, const float* __restrict__ Xk, const float* __restrict__ Xv,
    const float* __restrict__ Wq, const float* __restrict__ Wk, const float* __restrict__ Wv,
    short* __restrict__ Qt, short* __restrict__ Kb, short* __restrict__ Vb)
{
    __shared__ short xs_s[32 * 260];            // proj only; pitch 260 (2-way free)
    __shared__ int isBool;                      // pack only
    const int bi = blockIdx.x;
    const int t = threadIdx.x;

    if (bi < 768) {
        // ---------------- proj_mfma ----------------
        const int inp = bi >> 8;                // 0=Q,1=K,2=V
        const int s0 = (bi & 255) * 32;
        {
            // coalesced: each wave-load instruction covers one full 1KB X row
            const float* xbase = ((inp == 0) ? Xq : (inp == 1) ? Xk : Xv) + (size_t)s0 * 256;
            #pragma unroll
            for (int u = 0; u < 8; ++u) {
                const int idx = u * 1024 + t * 4;   // linear float index in 32x256 tile
                const int row = idx >> 8, col = idx & 255;
                float4 xv = *(const float4*)(xbase + idx);
                short4v o = { f2bf(xv.x), f2bf(xv.y), f2bf(xv.z), f2bf(xv.w) };
                *(short4v*)&xs_s[row * 260 + col] = o;
            }
        }

        const int wave = t >> 6, lane = t & 63;
        const int lq = lane & 31, hi = lane >> 5;
        const int c = wave * 32 + lq;           // out col 0..127

        // per-lane W fragments from f32 (lane-consecutive in c; L2-hot)
        const float* W = (inp == 0) ? Wq : (inp == 1) ? Wk : Wv;
        const float scale = (inp == 0) ? 0.25f * L2E : 1.0f;   // fold 1/sqrt(dk)*log2e into Wq
        Frag wf[16];
        #pragma unroll
        for (int kb = 0; kb < 16; ++kb) {
            const int k0 = kb * 16 + 4 * hi;
            union { bf16x8 v; short s[8]; } o;
            #pragma unroll
            for (int e = 0; e < 4; ++e) {
                o.s[e]     = f2bf(W[(size_t)(k0 + e) * DP + c] * scale);
                o.s[4 + e] = f2bf(W[(size_t)(k0 + 8 + e) * DP + c] * scale);
            }
            wf[kb].v = o.v;
        }
        __syncthreads();

        f32x16 acc;
        #pragma unroll
        for (int i = 0; i < 16; ++i) acc[i] = 0.f;

        #pragma unroll
        for (int kb = 0; kb < 16; ++kb) {
            Frag af;
            af.h2[0] = *(const short4v*)&xs_s[lq * 260 + kb*16 + 4*hi];
            af.h2[1] = *(const short4v*)&xs_s[lq * 260 + kb*16 + 8 + 4*hi];
            acc = __builtin_amdgcn_mfma_f32_32x32x16_bf16(af.v, wf[kb].v, acc, 0, 0, 0);
        }

        // D: col(lane&31)=c, row(reg r)=s0 + (r&3)+8*(r>>2)+4*hi
        const int b = s0 >> 11, sl = s0 & (S_LEN - 1);
        const int h = c >> 4, d = c & 15;
        if (inp == 1) {
            #pragma unroll
            for (int r = 0; r < 16; ++r) {
                const int s = sl + (r & 3) + 8*(r >> 2) + 4*hi;
                Kb[(((size_t)(b * NH + h)) * S_LEN + s) * DK + d] = f2bf(acc[r]);
            }
        } else {
            short* base = (inp == 0)
                ? Qt + (((size_t)(b * NH + h)) * 16 + d) * S_LEN + sl
                : Vb + (((size_t)(b * NH + h)) * 32 + d) * S_LEN + sl;
            #pragma unroll
            for (int g = 0; g < 4; ++g) {
                short4v vv = { f2bf(acc[4*g]), f2bf(acc[4*g+1]), f2bf(acc[4*g+2]), f2bf(acc[4*g+3]) };
                *(short4v*)(base + 8*g + 4*hi) = vv;
            }
        }
    } else if (bi < 1280) {
        // ---------------- vinit: V ones-rows 16,20 = 1.0 ----------------
        const int tid = (bi - 768) * 256 + t;   // 131072 total
        const int bh = tid >> 12;
        const int rem = tid & 4095;
        const int row = 16 + (rem >> 11) * 4;   // 16 or 20
        const int s = rem & 2047;
        Vb[((size_t)bh * 32 + row) * S_LEN + s] = (short)0x3F80;  // bf16 1.0
    } else {
        // ---------------- pack_mask: uint4 loads -> PLAIN bit layout -------
        const int lane = t & 63;
        const size_t kbase0 = (size_t)(bi - 1280) * 4096;        // block: 4096 keys
        const size_t kbase = kbase0 + (size_t)(t >> 6) * 1024;   // wave: 1024 keys

        // one 16B load covers this lane's 16 bool bytes (keys 16*lane..+15)
        union { uint4 v; unsigned u[4]; } uu;
        uu.v = *(const uint4*)((const unsigned char*)mraw + kbase + 16 * lane);

        if (t == 0) isBool = 0;
        __syncthreads();
        // bool 0/1 byte stream -> high bytes nonzero w.h.p.; int32 0/1 -> never
        if ((uu.u[0] | uu.u[1] | uu.u[2] | uu.u[3]) & 0xFFFFFF00u) isBool = 1;
        __syncthreads();

        // compress this lane's 16 bytes -> 16-bit mask (bit b = byte b != 0)
        unsigned val16;
        if (isBool) {
            unsigned n0 = ((uu.u[0] & 0x01010101u) * 0x01020408u) >> 24;
            unsigned n1 = ((uu.u[1] & 0x01010101u) * 0x01020408u) >> 24;
            unsigned n2 = ((uu.u[2] & 0x01010101u) * 0x01020408u) >> 24;
            unsigned n3 = ((uu.u[3] & 0x01010101u) * 0x01020408u) >> 24;
            val16 = n0 | (n1 << 4) | (n2 << 8) | (n3 << 12);
        } else {
            // int32 fallback (dead in practice): same key->bit mapping
            const int* p = (const int*)mraw + kbase + 16 * lane;
            val16 = 0;
            #pragma unroll
            for (int cc = 0; cc < 16; ++cc) val16 |= (p[cc] != 0 ? 1u : 0u) << cc;
        }

        // plain word w = keys 64w..64w+63 = lanes 4w..4w+3 (16 bits each)
        const int src0 = (4 * lane) & 63;
        const unsigned a0 = (unsigned)__shfl((int)val16, src0);
        const unsigned a1 = (unsigned)__shfl((int)val16, src0 + 1);
        const unsigned a2 = (unsigned)__shfl((int)val16, src0 + 2);
        const unsigned a3 = (unsigned)__shfl((int)val16, src0 + 3);

        if (lane < 16) {
            const unsigned long long w64 =
                (unsigned long long)a0 | ((unsigned long long)a1 << 16) |
                ((unsigned long long)a2 << 32) | ((unsigned long long)a3 << 48);
            const size_t row = kbase >> 11;               // b*S + q
            const int w0 = (int)(kbase & 2047) >> 6;      // first word idx (0 or 16)
            ms64[row * 32 + w0 + lane] = w64;             // one 128B store/wave
        }
    }
}

// ---------------- Kernel B: MFMA flash attention, LDS-staged K/V -----------
// grid (S/128, B*H, ns); block 256 = 4 waves x 32 q-rows. (r17's proven body)
__global__ __launch_bounds__(256, 8) void attn_mfma(
    const short* __restrict__ Qt, const short* __restrict__ Kb, const short* __restrict__ Vb,
    const unsigned long long* __restrict__ ms64, float* __restrict__ pacc, float* __restrict__ pl)
{
    __shared__ short kt_s[128 * 20];   // K tile: pitch 20 shorts (10 dw)
    __shared__ short vt_s[32 * 132];   // V^T tile: pitch 132 shorts (66 dw)

    const int bh = blockIdx.y;
    const int b = bh >> 3;
    const int z = blockIdx.z;
    const int t = threadIdx.x;
    const int wave = t >> 6, lane = t & 63;
    const int lq = lane & 31, hi = lane >> 5;
    const int qrow = blockIdx.x * 128 + wave * 32 + lq;

    Frag qf;
    {
        // Q^T [bh][16][S]: 8 scalar reads, coalesced across lanes (qrow = ..+lq)
        const short* qt = Qt + (size_t)bh * 16 * S_LEN + qrow;
        #pragma unroll
        for (int j = 0; j < 4; ++j) {
            qf.h2[0][j] = qt[(size_t)(4*hi + j) * S_LEN];
            qf.h2[1][j] = qt[(size_t)(8 + 4*hi + j) * S_LEN];
        }
    }

    f32x16 acc;
    #pragma unroll
    for (int i = 0; i < 16; ++i) acc[i] = 0.f;

    const short* kbase = Kb + (size_t)bh * S_LEN * DK;
    const short* vbase = Vb + (size_t)bh * 32 * S_LEN;
    const unsigned long long* mrow = ms64 + ((size_t)b * S_LEN + qrow) * 32;  // row-major

    const int tiles = (S_LEN / 128) / gridDim.z;
    const int t0 = z * tiles, t1 = t0 + tiles;

    for (int tile = t0; tile < t1; ++tile) {
        const int k0 = tile * 128;

        // ---- stage K tile (4KB, contiguous) and V^T tile (8.25KB)
        {
            const uint4 kv = *(const uint4*)(kbase + (size_t)k0 * DK + t * 8);
            short* kdst = &kt_s[(t >> 1) * 20 + (t & 1) * 8];
            *(uint2*)(kdst)     = *(uint2*)&kv;
            *(uint2*)(kdst + 4) = *((uint2*)&kv + 1);

            const short* vsrc = vbase + (size_t)(t >> 3) * S_LEN + k0 + (t & 7) * 16;
            uint4 v0 = *(const uint4*)(vsrc);
            uint4 v1 = *(const uint4*)(vsrc + 8);
            short* vdst = &vt_s[(t >> 3) * 132 + (t & 7) * 16];
            *(uint2*)(vdst)      = *(uint2*)&v0;
            *(uint2*)(vdst + 4)  = *((uint2*)&v0 + 1);
            *(uint2*)(vdst + 8)  = *(uint2*)&v1;
            *(uint2*)(vdst + 12) = *((uint2*)&v1 + 1);
        }
        __syncthreads();

        // two plain-bit u64 words (16B, per-lane) cover this 128-key tile
        const ulonglong2 mw = *(const ulonglong2*)(mrow + tile * 2);
        const unsigned long long W64a = mw.x, W64b = mw.y;

        #pragma unroll
        for (int kt = 0; kt < 4; ++kt) {
            // mask bits: key(r) = 32*(kt&1) + 4*hi + (r&3)+8*(r>>2) within word kt>>1
            const unsigned int W = (unsigned int)(((kt < 2) ? W64a : W64b)
                                                  >> (32*(kt & 1) + 4*hi));
            f32x16 ci;
            #pragma unroll
            for (int r = 0; r < 16; ++r) {
                const int bit = (r & 3) + 8*(r >> 2);
                ci[r] = __int_as_float(((int)(W << (31 - bit)) >> 31) & 0xC2C80000);
            }

            // QK^T for 32 keys (log2-domain scores via scaled Wq)
            Frag kf;
            kf.h2[0] = *(const short4v*)&kt_s[(kt*32 + lq) * 20 + 4*hi];
            kf.h2[1] = *(const short4v*)&kt_s[(kt*32 + lq) * 20 + 8 + 4*hi];
            f32x16 p = __builtin_amdgcn_mfma_f32_32x32x16_bf16(kf.v, qf.v, ci, 0, 0, 0);

            #pragma unroll
            for (int r = 0; r < 16; ++r) p[r] = __builtin_amdgcn_exp2f(p[r]);

            // PV: 2 MFMAs of 16 keys; packed bf16 convert (1 instr / 2 vals)
            #pragma unroll
            for (int j = 0; j < 2; ++j) {
                union { bf16x8 v; unsigned int u[4]; } pf;
                #pragma unroll
                for (int e = 0; e < 4; ++e) {
                    asm("v_cvt_pk_bf16_f32 %0, %1, %2"
                        : "=v"(pf.u[e]) : "v"(p[j*8 + 2*e]), "v"(p[j*8 + 2*e + 1]));
                }
                Frag vf;
                const int vo = lq * 132 + (kt*2 + j) * 16 + 4*hi;
                vf.h2[0] = *(const short4v*)&vt_s[vo];
                vf.h2[1] = *(const short4v*)&vt_s[vo + 8];
                acc = __builtin_amdgcn_mfma_f32_32x32x16_bf16(vf.v, pf.v, acc, 0, 0, 0);
            }
        }
        __syncthreads();   // protect LDS before next tile's stage
    }

    // partial store (unnormalized); acc[8] = sum of P (ones-row of V)
    float* pb = pacc + (((size_t)z * (BATCH*NH) + bh) * S_LEN + qrow) * 16;
    float4 o1 = { acc[0], acc[1], acc[2], acc[3] };
    float4 o2 = { acc[4], acc[5], acc[6], acc[7] };
    *(float4*)(pb + 4*hi) = o1;
    *(float4*)(pb + 8 + 4*hi) = o2;
    if (hi == 0) pl[((size_t)z * (BATCH*NH) + bh) * S_LEN + qrow] = acc[8];
}

// ---------------- Kernel C: combine + FC (ctx @ Wfc) + LayerNorm -----------
__global__ __launch_bounds__(256) void fc_ln(
    const float* __restrict__ pacc, const float* __restrict__ pl, int ns,
    const float* __restrict__ Wfc,
    const float* __restrict__ gamma, const float* __restrict__ beta,
    float* __restrict__ out)
{
    __shared__ float cs[8][DP];
    __shared__ float ys[8][256];
    __shared__ float red[16];
    const int t = threadIdx.x;
    const int row0 = blockIdx.x * 8;

    {
        const int idx = t * 4;
        const int r = idx >> 7, k = idx & 127;       // r 0..7, k mult of 4
        const int grow = row0 + r;
        const int b = grow >> 11, q = grow & (S_LEN - 1);
        const int h = k >> 4, d0 = k & 15;           // d0 in {0,4,8,12}
        float4 s = {0.f, 0.f, 0.f, 0.f};
        float L = 0.f;
        for (int z = 0; z < ns; ++z) {
            const size_t o = ((size_t)z * (BATCH*NH) + b * NH + h) * S_LEN + q;
            const float4 a = *(const float4*)(pacc + o * 16 + d0);
            s.x += a.x; s.y += a.y; s.z += a.z; s.w += a.w;
            L += pl[o];
        }
        const float inv = 1.0f / L;
        float4 o4 = { s.x * inv, s.y * inv, s.z * inv, s.w * inv };
        *(float4*)&cs[r][k] = o4;
    }
    __syncthreads();

    float acc[8] = {0,0,0,0,0,0,0,0};
    for (int k = 0; k < DP; k += 4) {
        const float w0 = Wfc[(k+0)*DM + t];
        const float w1 = Wfc[(k+1)*DM + t];
        const float w2 = Wfc[(k+2)*DM + t];
        const float w3 = Wfc[(k+3)*DM + t];
        #pragma unroll
        for (int r = 0; r < 8; ++r) {
            float4 x = *(const float4*)&cs[r][k];
            acc[r] = fmaf(x.x, w0, fmaf(x.y, w1, fmaf(x.z, w2, fmaf(x.w, w3, acc[r]))));
        }
    }

    #pragma unroll
    for (int r = 0; r < 8; ++r) ys[r][t] = acc[r];
    __syncthreads();

    const int w = t >> 6, lj = t & 63;
    #pragma unroll
    for (int rr = 0; rr < 2; ++rr) {
        const int r = w * 2 + rr;
        float a0 = ys[r][lj], a1 = ys[r][lj+64], a2 = ys[r][lj+128], a3 = ys[r][lj+192];
        float s1 = a0 + a1 + a2 + a3;
        float s2 = a0*a0 + a1*a1 + a2*a2 + a3*a3;
        #pragma unroll
        for (int off = 32; off; off >>= 1) {
            s1 += __shfl_xor(s1, off);
            s2 += __shfl_xor(s2, off);
        }
        if (lj == 0) {
            float mu = s1 * (1.0f/256.0f);
            float var = s2 * (1.0f/256.0f) - mu*mu;
            red[r*2]     = mu;
            red[r*2 + 1] = rsqrtf(var + 1e-5f);
        }
    }
    __syncthreads();

    const float g = gamma[t], be = beta[t];
    #pragma unroll
    for (int r = 0; r < 8; ++r) {
        float y = (acc[r] - red[r*2]) * red[r*2 + 1];
        out[(size_t)(row0 + r) * DM + t] = fmaf(y, g, be);
    }
}

extern "C" void kernel_launch(void* const* d_in, const int* in_sizes, int n_in,
                              void* d_out, int out_size, void* d_ws, size_t ws_size,
                              hipStream_t stream)
{
    const float* Xq = (const float*)d_in[0];
    const float* Xk = (const float*)d_in[1];
    const float* Xv = (const float*)d_in[2];
    const void* mask_raw = d_in[3];
    const float* Wq  = (const float*)d_in[4];
    const float* Wk  = (const float*)d_in[5];
    const float* Wv  = (const float*)d_in[6];
    const float* Wfc = (const float*)d_in[7];
    const float* gamma = (const float*)d_in[8];
    const float* beta  = (const float*)d_in[9];
    float* out = (float*)d_out;

    const size_t headsz = (size_t)BATCH * NH * S_LEN * DK;      // 1,048,576 elems
    const size_t maskelems = (size_t)BATCH * S_LEN * S_LEN;     // 16.8M

    char* wsb = (char*)d_ws;
    short* Qt = (short*)wsb;                              // 2 MB ([bh][16][S])
    short* Kb = Qt + headsz;                              // 2 MB ([bh][S][16])
    short* Vb = Kb + headsz;                              // 4 MB ([bh][32][S])
    unsigned long long* msk = (unsigned long long*)(Vb + 2 * headsz);  // 2 MB plain row-major
    float* pacc = (float*)(msk + maskelems / 64);
    size_t ns = 4;
    {
        const size_t fixed = (size_t)((char*)pacc - wsb);
        while (ns > 1 && fixed + ns * ((size_t)BATCH*NH*S_LEN*17*4) > ws_size)
            ns >>= 1;
    }
    float* pl = pacc + ns * (size_t)BATCH * NH * S_LEN * 16;

    main1<<<dim3(768 + 512 + (unsigned)(maskelems / 4096)), dim3(256), 0, stream>>>(
        mask_raw, msk, Xq, Xk, Xv, Wq, Wk, Wv, Qt, Kb, Vb);
    attn_mfma<<<dim3(S_LEN / 128, BATCH * NH, (unsigned)ns), dim3(256), 0, stream>>>(
        Qt, Kb, Vb, msk, pacc, pl);
    fc_ln<<<dim3(BATCH * S_LEN / 8), dim3(256), 0, stream>>>(pacc, pl, (int)ns, Wfc, gamma, beta, out);
}

// Round 21
// 70.938 us; speedup vs baseline: 1.3237x; 1.0053x over previous
//
#include <hip/hip_runtime.h>
#include <hip/hip_bf16.h>

#define S_LEN 2048
#define BATCH 4
#define NH 8
#define DK 16
#define DM 256
#define DP 128           // NH*DK
#define L2E 1.4426950408889634f

typedef short bf16x8 __attribute__((ext_vector_type(8)));
typedef short short4v __attribute__((ext_vector_type(4)));
typedef float f32x16 __attribute__((ext_vector_type(16)));

__device__ __forceinline__ short f2bf(float x) {
    __hip_bfloat16 h = __float2bfloat16(x);
    return __builtin_bit_cast(short, h);
}
__device__ __forceinline__ float bf2f(short x) {
    return __int_as_float(((int)(unsigned short)x) << 16);
}

union Frag { bf16x8 v; short4v h2[2]; };

// ---------------- Kernel A: main1 = proj_mfma U vinit U pack_mask ----------
// [0,768): proj (in-register W gather); [768,1280): vinit; [1280,5376): pack.
// pack emits the PLAIN row-major bitmask (bit j of word w = mask[row][64w+j]).
__global__ __launch_bounds__(256) void main1(
    const void* __restrict__ mraw, unsigned long long* __restrict__ ms64,
    const float* __restrict__ Xq, const float* __restrict__ Xk, const float* __restrict__ Xv,
    const float* __restrict__ Wq, const float* __restrict__ Wk, const float* __restrict__ Wv,
    short* __restrict__ Qt, short* __restrict__ Kb, short* __restrict__ Vb)
{
    __shared__ short xs_s[32 * 260];            // proj only; pitch 260 (2-way free)
    __shared__ int isBool;                      // pack only
    const int bi = blockIdx.x;
    const int t = threadIdx.x;

    if (bi < 768) {
        // ---------------- proj_mfma ----------------
        const int inp = bi >> 8;                // 0=Q,1=K,2=V
        const int s0 = (bi & 255) * 32;
        {
            // coalesced: each wave-load instruction covers one full 1KB X row
            const float* xbase = ((inp == 0) ? Xq : (inp == 1) ? Xk : Xv) + (size_t)s0 * 256;
            #pragma unroll
            for (int u = 0; u < 8; ++u) {
                const int idx = u * 1024 + t * 4;   // linear float index in 32x256 tile
                const int row = idx >> 8, col = idx & 255;
                float4 xv = *(const float4*)(xbase + idx);
                short4v o = { f2bf(xv.x), f2bf(xv.y), f2bf(xv.z), f2bf(xv.w) };
                *(short4v*)&xs_s[row * 260 + col] = o;
            }
        }

        const int wave = t >> 6, lane = t & 63;
        const int lq = lane & 31, hi = lane >> 5;
        const int c = wave * 32 + lq;           // out col 0..127

        // per-lane W fragments from f32 (lane-consecutive in c; L2-hot)
        const float* W = (inp == 0) ? Wq : (inp == 1) ? Wk : Wv;
        const float scale = (inp == 0) ? 0.25f * L2E : 1.0f;   // fold 1/sqrt(dk)*log2e into Wq
        Frag wf[16];
        #pragma unroll
        for (int kb = 0; kb < 16; ++kb) {
            const int k0 = kb * 16 + 4 * hi;
            union { bf16x8 v; short s[8]; } o;
            #pragma unroll
            for (int e = 0; e < 4; ++e) {
                o.s[e]     = f2bf(W[(size_t)(k0 + e) * DP + c] * scale);
                o.s[4 + e] = f2bf(W[(size_t)(k0 + 8 + e) * DP + c] * scale);
            }
            wf[kb].v = o.v;
        }
        __syncthreads();

        f32x16 acc;
        #pragma unroll
        for (int i = 0; i < 16; ++i) acc[i] = 0.f;

        #pragma unroll
        for (int kb = 0; kb < 16; ++kb) {
            Frag af;
            af.h2[0] = *(const short4v*)&xs_s[lq * 260 + kb*16 + 4*hi];
            af.h2[1] = *(const short4v*)&xs_s[lq * 260 + kb*16 + 8 + 4*hi];
            acc = __builtin_amdgcn_mfma_f32_32x32x16_bf16(af.v, wf[kb].v, acc, 0, 0, 0);
        }

        // D: col(lane&31)=c, row(reg r)=s0 + (r&3)+8*(r>>2)+4*hi
        const int b = s0 >> 11, sl = s0 & (S_LEN - 1);
        const int h = c >> 4, d = c & 15;
        if (inp == 1) {
            #pragma unroll
            for (int r = 0; r < 16; ++r) {
                const int s = sl + (r & 3) + 8*(r >> 2) + 4*hi;
                Kb[(((size_t)(b * NH + h)) * S_LEN + s) * DK + d] = f2bf(acc[r]);
            }
        } else {
            short* base = (inp == 0)
                ? Qt + (((size_t)(b * NH + h)) * 16 + d) * S_LEN + sl
                : Vb + (((size_t)(b * NH + h)) * 32 + d) * S_LEN + sl;
            #pragma unroll
            for (int g = 0; g < 4; ++g) {
                short4v vv = { f2bf(acc[4*g]), f2bf(acc[4*g+1]), f2bf(acc[4*g+2]), f2bf(acc[4*g+3]) };
                *(short4v*)(base + 8*g + 4*hi) = vv;
            }
        }
    } else if (bi < 1280) {
        // ---------------- vinit: V ones-rows 16,20 = 1.0 ----------------
        const int tid = (bi - 768) * 256 + t;   // 131072 total
        const int bh = tid >> 12;
        const int rem = tid & 4095;
        const int row = 16 + (rem >> 11) * 4;   // 16 or 20
        const int s = rem & 2047;
        Vb[((size_t)bh * 32 + row) * S_LEN + s] = (short)0x3F80;  // bf16 1.0
    } else {
        // ---------------- pack_mask: uint4 loads -> PLAIN bit layout -------
        const int lane = t & 63;
        const size_t kbase0 = (size_t)(bi - 1280) * 4096;        // block: 4096 keys
        const size_t kbase = kbase0 + (size_t)(t >> 6) * 1024;   // wave: 1024 keys

        union { uint4 v; unsigned u[4]; } uu;
        uu.v = *(const uint4*)((const unsigned char*)mraw + kbase + 16 * lane);

        if (t == 0) isBool = 0;
        __syncthreads();
        if ((uu.u[0] | uu.u[1] | uu.u[2] | uu.u[3]) & 0xFFFFFF00u) isBool = 1;
        __syncthreads();

        unsigned val16;
        if (isBool) {
            unsigned n0 = ((uu.u[0] & 0x01010101u) * 0x01020408u) >> 24;
            unsigned n1 = ((uu.u[1] & 0x01010101u) * 0x01020408u) >> 24;
            unsigned n2 = ((uu.u[2] & 0x01010101u) * 0x01020408u) >> 24;
            unsigned n3 = ((uu.u[3] & 0x01010101u) * 0x01020408u) >> 24;
            val16 = n0 | (n1 << 4) | (n2 << 8) | (n3 << 12);
        } else {
            const int* p = (const int*)mraw + kbase + 16 * lane;
            val16 = 0;
            #pragma unroll
            for (int cc = 0; cc < 16; ++cc) val16 |= (p[cc] != 0 ? 1u : 0u) << cc;
        }

        const int src0 = (4 * lane) & 63;
        const unsigned a0 = (unsigned)__shfl((int)val16, src0);
        const unsigned a1 = (unsigned)__shfl((int)val16, src0 + 1);
        const unsigned a2 = (unsigned)__shfl((int)val16, src0 + 2);
        const unsigned a3 = (unsigned)__shfl((int)val16, src0 + 3);

        if (lane < 16) {
            const unsigned long long w64 =
                (unsigned long long)a0 | ((unsigned long long)a1 << 16) |
                ((unsigned long long)a2 << 32) | ((unsigned long long)a3 << 48);
            const size_t row = kbase >> 11;               // b*S + q
            const int w0 = (int)(kbase & 2047) >> 6;      // first word idx (0 or 16)
            ms64[row * 32 + w0 + lane] = w64;             // one 128B store/wave
        }
    }
}

// ---------------- Kernel B: MFMA flash attention, LDS-staged K/V -----------
// grid (S/128, B*H, ns); block 256 = 4 waves x 32 q-rows. bf16 partials.
__global__ __launch_bounds__(256, 8) void attn_mfma(
    const short* __restrict__ Qt, const short* __restrict__ Kb, const short* __restrict__ Vb,
    const unsigned long long* __restrict__ ms64, short* __restrict__ paccb, float* __restrict__ pl)
{
    __shared__ short kt_s[128 * 20];   // K tile: pitch 20 shorts (10 dw)
    __shared__ short vt_s[32 * 132];   // V^T tile: pitch 132 shorts (66 dw)

    const int bh = blockIdx.y;
    const int b = bh >> 3;
    const int z = blockIdx.z;
    const int t = threadIdx.x;
    const int wave = t >> 6, lane = t & 63;
    const int lq = lane & 31, hi = lane >> 5;
    const int qrow = blockIdx.x * 128 + wave * 32 + lq;

    Frag qf;
    {
        const short* qt = Qt + (size_t)bh * 16 * S_LEN + qrow;
        #pragma unroll
        for (int j = 0; j < 4; ++j) {
            qf.h2[0][j] = qt[(size_t)(4*hi + j) * S_LEN];
            qf.h2[1][j] = qt[(size_t)(8 + 4*hi + j) * S_LEN];
        }
    }

    f32x16 acc;
    #pragma unroll
    for (int i = 0; i < 16; ++i) acc[i] = 0.f;

    const short* kbase = Kb + (size_t)bh * S_LEN * DK;
    const short* vbase = Vb + (size_t)bh * 32 * S_LEN;
    const unsigned long long* mrow = ms64 + ((size_t)b * S_LEN + qrow) * 32;

    const int tiles = (S_LEN / 128) / gridDim.z;
    const int t0 = z * tiles, t1 = t0 + tiles;

    for (int tile = t0; tile < t1; ++tile) {
        const int k0 = tile * 128;
        {
            const uint4 kv = *(const uint4*)(kbase + (size_t)k0 * DK + t * 8);
            short* kdst = &kt_s[(t >> 1) * 20 + (t & 1) * 8];
            *(uint2*)(kdst)     = *(uint2*)&kv;
            *(uint2*)(kdst + 4) = *((uint2*)&kv + 1);

            const short* vsrc = vbase + (size_t)(t >> 3) * S_LEN + k0 + (t & 7) * 16;
            uint4 v0 = *(const uint4*)(vsrc);
            uint4 v1 = *(const uint4*)(vsrc + 8);
            short* vdst = &vt_s[(t >> 3) * 132 + (t & 7) * 16];
            *(uint2*)(vdst)      = *(uint2*)&v0;
            *(uint2*)(vdst + 4)  = *((uint2*)&v0 + 1);
            *(uint2*)(vdst + 8)  = *(uint2*)&v1;
            *(uint2*)(vdst + 12) = *((uint2*)&v1 + 1);
        }
        __syncthreads();

        const ulonglong2 mw = *(const ulonglong2*)(mrow + tile * 2);
        const unsigned long long W64a = mw.x, W64b = mw.y;

        #pragma unroll
        for (int kt = 0; kt < 4; ++kt) {
            const unsigned int W = (unsigned int)(((kt < 2) ? W64a : W64b)
                                                  >> (32*(kt & 1) + 4*hi));
            f32x16 ci;
            #pragma unroll
            for (int r = 0; r < 16; ++r) {
                const int bit = (r & 3) + 8*(r >> 2);
                ci[r] = __int_as_float(((int)(W << (31 - bit)) >> 31) & 0xC2C80000);
            }

            Frag kf;
            kf.h2[0] = *(const short4v*)&kt_s[(kt*32 + lq) * 20 + 4*hi];
            kf.h2[1] = *(const short4v*)&kt_s[(kt*32 + lq) * 20 + 8 + 4*hi];
            f32x16 p = __builtin_amdgcn_mfma_f32_32x32x16_bf16(kf.v, qf.v, ci, 0, 0, 0);

            #pragma unroll
            for (int r = 0; r < 16; ++r) p[r] = __builtin_amdgcn_exp2f(p[r]);

            #pragma unroll
            for (int j = 0; j < 2; ++j) {
                union { bf16x8 v; unsigned int u[4]; } pf;
                #pragma unroll
                for (int e = 0; e < 4; ++e) {
                    asm("v_cvt_pk_bf16_f32 %0, %1, %2"
                        : "=v"(pf.u[e]) : "v"(p[j*8 + 2*e]), "v"(p[j*8 + 2*e + 1]));
                }
                Frag vf;
                const int vo = lq * 132 + (kt*2 + j) * 16 + 4*hi;
                vf.h2[0] = *(const short4v*)&vt_s[vo];
                vf.h2[1] = *(const short4v*)&vt_s[vo + 8];
                acc = __builtin_amdgcn_mfma_f32_32x32x16_bf16(vf.v, pf.v, acc, 0, 0, 0);
            }
        }
        __syncthreads();
    }

    // partial store in bf16 (RNE); acc[8] = sum of P (ones-row of V) stays f32
    short* pb = paccb + (((size_t)z * (BATCH*NH) + bh) * S_LEN + qrow) * 16;
    union { short4v h; unsigned u[2]; } o1, o2;
    asm("v_cvt_pk_bf16_f32 %0, %1, %2" : "=v"(o1.u[0]) : "v"(acc[0]), "v"(acc[1]));
    asm("v_cvt_pk_bf16_f32 %0, %1, %2" : "=v"(o1.u[1]) : "v"(acc[2]), "v"(acc[3]));
    asm("v_cvt_pk_bf16_f32 %0, %1, %2" : "=v"(o2.u[0]) : "v"(acc[4]), "v"(acc[5]));
    asm("v_cvt_pk_bf16_f32 %0, %1, %2" : "=v"(o2.u[1]) : "v"(acc[6]), "v"(acc[7]));
    *(short4v*)(pb + 4*hi) = o1.h;
    *(short4v*)(pb + 8 + 4*hi) = o2.h;
    if (hi == 0) pl[((size_t)z * (BATCH*NH) + bh) * S_LEN + qrow] = acc[8];
}

// ---------------- Kernel C: combine + FC (ctx @ Wfc) + LayerNorm -----------
// 16 rows per block (512 blocks); bf16 partial combine folded into staging.
__global__ __launch_bounds__(256) void fc_ln(
    const short* __restrict__ paccb, const float* __restrict__ pl, int ns,
    const float* __restrict__ Wfc,
    const float* __restrict__ gamma, const float* __restrict__ beta,
    float* __restrict__ out)
{
    __shared__ float cs[16][DP];
    __shared__ float ys[16][256];
    __shared__ float red[32];
    const int t = threadIdx.x;
    const int row0 = blockIdx.x * 16;

    {
        const int idx = t * 8;
        const int r = idx >> 7, k = idx & 127;       // r 0..15, k mult of 8
        const int grow = row0 + r;
        const int b = grow >> 11, q = grow & (S_LEN - 1);
        const int h = k >> 4, d0 = k & 15;           // d0 in {0,8}
        float s[8] = {0,0,0,0,0,0,0,0};
        float L = 0.f;
        for (int z = 0; z < ns; ++z) {
            const size_t o = ((size_t)z * (BATCH*NH) + b * NH + h) * S_LEN + q;
            const short4v a0 = *(const short4v*)(paccb + o * 16 + d0);
            const short4v a1 = *(const short4v*)(paccb + o * 16 + d0 + 4);
            #pragma unroll
            for (int i = 0; i < 4; ++i) {
                s[i]     += bf2f(a0[i]);
                s[4 + i] += bf2f(a1[i]);
            }
            L += pl[o];
        }
        const float inv = 1.0f / L;
        #pragma unroll
        for (int i = 0; i < 8; ++i) cs[r][k + i] = s[i] * inv;
    }
    __syncthreads();

    float acc[16];
    #pragma unroll
    for (int r = 0; r < 16; ++r) acc[r] = 0.f;
    for (int k = 0; k < DP; k += 4) {
        const float w0 = Wfc[(k+0)*DM + t];
        const float w1 = Wfc[(k+1)*DM + t];
        const float w2 = Wfc[(k+2)*DM + t];
        const float w3 = Wfc[(k+3)*DM + t];
        #pragma unroll
        for (int r = 0; r < 16; ++r) {
            float4 x = *(const float4*)&cs[r][k];
            acc[r] = fmaf(x.x, w0, fmaf(x.y, w1, fmaf(x.z, w2, fmaf(x.w, w3, acc[r]))));
        }
    }

    #pragma unroll
    for (int r = 0; r < 16; ++r) ys[r][t] = acc[r];
    __syncthreads();

    const int w = t >> 6, lj = t & 63;
    #pragma unroll
    for (int rr = 0; rr < 4; ++rr) {
        const int r = w * 4 + rr;
        float a0 = ys[r][lj], a1 = ys[r][lj+64], a2 = ys[r][lj+128], a3 = ys[r][lj+192];
        float s1 = a0 + a1 + a2 + a3;
        float s2 = a0*a0 + a1*a1 + a2*a2 + a3*a3;
        #pragma unroll
        for (int off = 32; off; off >>= 1) {
            s1 += __shfl_xor(s1, off);
            s2 += __shfl_xor(s2, off);
        }
        if (lj == 0) {
            float mu = s1 * (1.0f/256.0f);
            float var = s2 * (1.0f/256.0f) - mu*mu;
            red[r*2]     = mu;
            red[r*2 + 1] = rsqrtf(var + 1e-5f);
        }
    }
    __syncthreads();

    const float g = gamma[t], be = beta[t];
    #pragma unroll
    for (int r = 0; r < 16; ++r) {
        float y = (acc[r] - red[r*2]) * red[r*2 + 1];
        out[(size_t)(row0 + r) * DM + t] = fmaf(y, g, be);
    }
}

extern "C" void kernel_launch(void* const* d_in, const int* in_sizes, int n_in,
                              void* d_out, int out_size, void* d_ws, size_t ws_size,
                              hipStream_t stream)
{
    const float* Xq = (const float*)d_in[0];
    const float* Xk = (const float*)d_in[1];
    const float* Xv = (const float*)d_in[2];
    const void* mask_raw = d_in[3];
    const float* Wq  = (const float*)d_in[4];
    const float* Wk  = (const float*)d_in[5];
    const float* Wv  = (const float*)d_in[6];
    const float* Wfc = (const float*)d_in[7];
    const float* gamma = (const float*)d_in[8];
    const float* beta  = (const float*)d_in[9];
    float* out = (float*)d_out;

    const size_t headsz = (size_t)BATCH * NH * S_LEN * DK;      // 1,048,576 elems
    const size_t maskelems = (size_t)BATCH * S_LEN * S_LEN;     // 16.8M

    char* wsb = (char*)d_ws;
    short* Qt = (short*)wsb;                              // 2 MB ([bh][16][S])
    short* Kb = Qt + headsz;                              // 2 MB ([bh][S][16])
    short* Vb = Kb + headsz;                              // 4 MB ([bh][32][S])
    unsigned long long* msk = (unsigned long long*)(Vb + 2 * headsz);  // 2 MB plain row-major
    short* paccb = (short*)(msk + maskelems / 64);        // bf16 partials
    size_t ns = 4;
    {
        const size_t fixed = (size_t)((char*)paccb - wsb);
        while (ns > 1 && fixed + ns * ((size_t)BATCH*NH*S_LEN*(16*2 + 4)) > ws_size)
            ns >>= 1;
    }
    float* pl = (float*)(paccb + ns * (size_t)BATCH * NH * S_LEN * 16);

    main1<<<dim3(768 + 512 + (unsigned)(maskelems / 4096)), dim3(256), 0, stream>>>(
        mask_raw, msk, Xq, Xk, Xv, Wq, Wk, Wv, Qt, Kb, Vb);
    attn_mfma<<<dim3(S_LEN / 128, BATCH * NH, (unsigned)ns), dim3(256), 0, stream>>>(
        Qt, Kb, Vb, msk, paccb, pl);
    fc_ln<<<dim3(BATCH * S_LEN / 16), dim3(256), 0, stream>>>(paccb, pl, (int)ns, Wfc, gamma, beta, out);
}